// Round 1
// baseline (134.420 us; speedup 1.0000x reference)
//
#include <hip/hip_runtime.h>

// ---------------- problem constants ----------------
// N=512 nodes/heads, F_IN=256, H=64, C=64, K=12, ALPHA=0.2
// d_in: X(512x256), W_stack(512x256x64), a_stack(512x128), W_out(32768x64), a_out(128), V(512x64)
// d_out: adj (512x512) followed by out (512x64), float32

// ---------------- ws float offsets ----------------
#define XT_OFF    0           // 131072 floats : X^T [256][512]
#define CAND_OFF  131072      // 3072 : per-block top-12 candidates
#define KTH_OFF   134144      // 1    : 12th largest of A
#define INT_OFF   134208      // 128 ints (as float slots)
#define MIDC_OFF  134400      // 12*32768 : compact mid rows
#define PART_OFF  527616      // 768*128  : Wh2 partials [o][block]
// int-region indices
#define I_CNT   0
#define I_ENT   8    // raw entries (i*512+j), up to 12
#define I_M     24
#define I_R     25
#define I_ROWS  32
#define I_ER    48
#define I_EJ    64
#define I_ECJ   80

__device__ __forceinline__ float leaky_(float x) { return fmaxf(x, 0.2f * x); }
__device__ __forceinline__ float elu_(float x)   { return x > 0.f ? x : __expf(x) - 1.f; }

// K1: A = V V^T -> d_out[0..262143]; X^T -> ws; zero out-section + counter
__global__ void k1_prep(const float* __restrict__ V, const float* __restrict__ X,
                        float* __restrict__ wsf, float* __restrict__ out) {
  int b = blockIdx.x, t = threadIdx.x;
  if (b < 512) {
    __shared__ float vi[64];
    if (t < 64) vi[t] = V[b * 64 + t];
    __syncthreads();
    #pragma unroll
    for (int jj = 0; jj < 2; ++jj) {
      int j = t + jj * 256;
      const float4* vj = reinterpret_cast<const float4*>(V + j * 64);
      float acc = 0.f;
      #pragma unroll
      for (int q = 0; q < 16; ++q) {
        float4 v4 = vj[q];
        acc += v4.x * vi[q*4] + v4.y * vi[q*4+1] + v4.z * vi[q*4+2] + v4.w * vi[q*4+3];
      }
      out[b * 512 + j] = acc;
    }
  } else if (b < 640) {
    int base = (b - 512) * 1024;
    #pragma unroll
    for (int q = 0; q < 4; ++q) {
      int o = base + q * 256 + t;
      int f = o >> 9, j = o & 511;
      wsf[XT_OFF + o] = X[j * 256 + f];
    }
  } else {
    int base = 262144 + (b - 640) * 512 + t;
    out[base] = 0.f;
    out[base + 256] = 0.f;
    if (b == 640 && t == 0) {
      int* ip = (int*)(wsf + INT_OFF);
      ip[I_CNT] = 0;
    }
  }
}

// K2: each block: top-12 of its 1024 A values (12 rounds argmax+remove, shuffle reduce)
__global__ void k2_topk_block(const float* __restrict__ A, float* __restrict__ wsf) {
  __shared__ float svw[4]; __shared__ int siw[4];
  int b = blockIdx.x, t = threadIdx.x;
  int l = t & 63, w = t >> 6;
  float4 v4 = *reinterpret_cast<const float4*>(A + b * 1024 + t * 4);
  float v0 = v4.x, v1 = v4.y, v2 = v4.z, v3 = v4.w;
  for (int round = 0; round < 12; ++round) {
    float m = v0; int mi = 0;
    if (v1 > m) { m = v1; mi = 1; }
    if (v2 > m) { m = v2; mi = 2; }
    if (v3 > m) { m = v3; mi = 3; }
    int idx = (t << 2) | mi;
    #pragma unroll
    for (int d = 1; d < 64; d <<= 1) {
      float ov = __shfl_xor(m, d);
      int   oi = __shfl_xor(idx, d);
      if (ov > m || (ov == m && oi < idx)) { m = ov; idx = oi; }
    }
    if (l == 0) { svw[w] = m; siw[w] = idx; }
    __syncthreads();
    float bm = svw[0]; int bi = siw[0];
    #pragma unroll
    for (int ww = 1; ww < 4; ++ww) {
      if (svw[ww] > bm || (svw[ww] == bm && siw[ww] < bi)) { bm = svw[ww]; bi = siw[ww]; }
    }
    if (t == 0) wsf[CAND_OFF + b * 12 + round] = bm;
    if ((bi >> 2) == t) {
      int q = bi & 3;
      if (q == 0) v0 = -INFINITY; else if (q == 1) v1 = -INFINITY;
      else if (q == 2) v2 = -INFINITY; else v3 = -INFINITY;
    }
    __syncthreads();
  }
}

// K3: 12th largest of the 3072 candidates -> ws[KTH_OFF]
__global__ void k3_topk_final(float* __restrict__ wsf) {
  __shared__ float svw[4]; __shared__ int siw[4];
  int t = threadIdx.x, l = t & 63, w = t >> 6;
  float v[12];
  #pragma unroll
  for (int q = 0; q < 12; ++q) v[q] = wsf[CAND_OFF + t * 12 + q];
  unsigned rm = 0;
  float kth = 0.f;
  for (int round = 0; round < 12; ++round) {
    float m = -INFINITY; int mi = 0;
    #pragma unroll
    for (int q = 0; q < 12; ++q) {
      bool ok = ((rm >> q) & 1u) == 0u;
      if (ok && v[q] > m) { m = v[q]; mi = q; }
    }
    int idx = (t << 4) | mi;
    #pragma unroll
    for (int d = 1; d < 64; d <<= 1) {
      float ov = __shfl_xor(m, d);
      int   oi = __shfl_xor(idx, d);
      if (ov > m || (ov == m && oi < idx)) { m = ov; idx = oi; }
    }
    if (l == 0) { svw[w] = m; siw[w] = idx; }
    __syncthreads();
    float bm = svw[0]; int bi = siw[0];
    #pragma unroll
    for (int ww = 1; ww < 4; ++ww) {
      if (svw[ww] > bm || (svw[ww] == bm && siw[ww] < bi)) { bm = svw[ww]; bi = siw[ww]; }
    }
    if ((bi >> 4) == t) rm |= 1u << (bi & 15);
    kth = bm;
    __syncthreads();
  }
  if (t == 0) wsf[KTH_OFF] = kth;
}

// K4: adj = (A > kth) in place in d_out; append nonzero linear indices (atomics)
__global__ void k4_adj(float* __restrict__ outAdj, float* __restrict__ wsf) {
  int b = blockIdx.x, t = threadIdx.x;
  float kth = wsf[KTH_OFF];
  int* ip = (int*)(wsf + INT_OFF);
  int base = b * 1024 + t * 4;
  float4 a = *reinterpret_cast<const float4*>(outAdj + base);
  float va[4] = { a.x, a.y, a.z, a.w };
  float ov[4];
  #pragma unroll
  for (int q = 0; q < 4; ++q) {
    bool one = va[q] > kth;
    ov[q] = one ? 1.f : 0.f;
    if (one) {
      int pos = atomicAdd(&ip[I_CNT], 1);
      if (pos < 12) ip[I_ENT + pos] = base + q;
    }
  }
  float4 o; o.x = ov[0]; o.y = ov[1]; o.z = ov[2]; o.w = ov[3];
  *reinterpret_cast<float4*>(outAdj + base) = o;
}

// K5: sort entries (canonical order -> determinism), build rows/er/ej/ecj header
__global__ void k5_finalize(float* __restrict__ wsf) {
  if (threadIdx.x != 0) return;
  int* ip = (int*)(wsf + INT_OFF);
  int cnt = ip[I_CNT];
  if (cnt > 12) cnt = 12;
  if (cnt < 0)  cnt = 0;
  int e[12];
  for (int m = 0; m < cnt; ++m) e[m] = ip[I_ENT + m];
  for (int a = 1; a < cnt; ++a) {
    int key = e[a]; int b = a - 1;
    while (b >= 0 && e[b] > key) { e[b + 1] = e[b]; --b; }
    e[b + 1] = key;
  }
  int R = 0; int rows[12], er_[12], ej_[12];
  for (int m = 0; m < cnt; ++m) {
    int i2 = e[m] >> 9, j2 = e[m] & 511;
    if (R == 0 || rows[R - 1] != i2) rows[R++] = i2;
    er_[m] = R - 1; ej_[m] = j2;
  }
  ip[I_M] = cnt; ip[I_R] = R;
  for (int r = 0; r < 12; ++r) ip[I_ROWS + r] = (r < R) ? rows[r] : 0;
  for (int m = 0; m < 12; ++m) {
    ip[I_ER + m] = (m < cnt) ? er_[m] : 0;
    ip[I_EJ + m] = (m < cnt) ? ej_[m] : 0;
    int cj = -1;
    if (m < cnt) { for (int r = 0; r < R; ++r) if (rows[r] == ej_[m]) cj = r; }
    ip[I_ECJ + m] = cj;
  }
}

// K6: one block per head h. Computes mid_c[r][h*64+k] = elu(sum_j A1[i_r,j] * (X W_h)[j,k])
__global__ __launch_bounds__(256, 4) void k6_heads(
    const float* __restrict__ X, const float* __restrict__ Wst,
    const float* __restrict__ ast, float* __restrict__ wsf) {
  __shared__ int   shdr[96];
  __shared__ float al[128];
  __shared__ float w1[256], w2[256];
  __shared__ __align__(16) float XeT[256 * 12];  // X rows of entry cols, f-major
  __shared__ float whp[4][768];
  __shared__ float wh_ent[768];                  // Wh[j_m][k]
  __shared__ float e2s[512];
  __shared__ float e1r[12], mr[12], sr[12], avals[12];
  __shared__ float red4[48], redw[4];

  int h = blockIdx.x, t = threadIdx.x;
  int l = t & 63, w = t >> 6;
  const int* ip = (const int*)(wsf + INT_OFF);
  if (t < 96)  shdr[t] = ip[t];
  if (t < 128) al[t] = ast[h * 128 + t];
  __syncthreads();
  int M = shdr[I_M], R = shdr[I_R];
  const float* Wb = Wst + h * 16384;

  // (a) w1[f] = sum_k W[f][k]*a1[k], w2[f] = sum_k W[f][k]*a2[k]  (coalesced W read)
  {
    int fg = l >> 4;
    int kc = (l & 15) << 2;
    #pragma unroll 4
    for (int it = 0; it < 16; ++it) {
      int f = w * 64 + it * 4 + fg;
      float4 wq = *reinterpret_cast<const float4*>(Wb + f * 64 + kc);
      float p1 = wq.x * al[kc] + wq.y * al[kc+1] + wq.z * al[kc+2] + wq.w * al[kc+3];
      float p2 = wq.x * al[64+kc] + wq.y * al[64+kc+1] + wq.z * al[64+kc+2] + wq.w * al[64+kc+3];
      #pragma unroll
      for (int d = 1; d < 16; d <<= 1) { p1 += __shfl_xor(p1, d); p2 += __shfl_xor(p2, d); }
      if ((l & 15) == 0) { w1[f] = p1; w2[f] = p2; }
    }
  }
  // stage X rows at entry columns, transposed (f-major) so (b) reads 3x b128 broadcasts
  #pragma unroll
  for (int m = 0; m < 12; ++m) {
    float v = 0.f;
    if (m < M) v = X[shdr[I_EJ + m] * 256 + t];
    XeT[t * 12 + m] = v;
  }
  __syncthreads();

  // (b) Wh[j_m][k] partial over this wave's f-chunk (W read from L2, coalesced)
  {
    float wh[12];
    #pragma unroll
    for (int m = 0; m < 12; ++m) wh[m] = 0.f;
    const float* Wb2 = Wb + w * 4096;
    #pragma unroll 2
    for (int i = 0; i < 64; ++i) {
      float wv = Wb2[i * 64 + l];
      const float4* xr = reinterpret_cast<const float4*>(&XeT[(w * 64 + i) * 12]);
      float4 xa = xr[0], xb = xr[1], xc = xr[2];
      wh[0] += xa.x * wv; wh[1] += xa.y * wv; wh[2]  += xa.z * wv; wh[3]  += xa.w * wv;
      wh[4] += xb.x * wv; wh[5] += xb.y * wv; wh[6]  += xb.z * wv; wh[7]  += xb.w * wv;
      wh[8] += xc.x * wv; wh[9] += xc.y * wv; wh[10] += xc.z * wv; wh[11] += xc.w * wv;
    }
    #pragma unroll
    for (int m = 0; m < 12; ++m) whp[w][m * 64 + l] = wh[m];
  }

  // e1 at adjacency rows (<=11 dots of length 256, wave-reduced)
  for (int r = w; r < R; r += 4) {
    int row = shdr[I_ROWS + r];
    float p = 0.f;
    #pragma unroll
    for (int s = 0; s < 4; ++s) {
      int f = s * 64 + l;
      p += X[row * 256 + f] * w1[f];
    }
    #pragma unroll
    for (int d = 1; d < 64; d <<= 1) p += __shfl_xor(p, d);
    if (l == 0) e1r[r] = p;
  }

  // e2 for all 512 nodes via X^T (coalesced)
  {
    const float2* XT2 = reinterpret_cast<const float2*>(wsf + XT_OFF);
    float a0 = 0.f, a1 = 0.f;
    #pragma unroll 4
    for (int f = 0; f < 256; ++f) {
      float2 xv = XT2[f * 256 + t];
      float wf = w2[f];
      a0 += xv.x * wf; a1 += xv.y * wf;
    }
    e2s[2 * t] = a0; e2s[2 * t + 1] = a1;
  }
  __syncthreads();

  // reduce Wh partials across waves
  for (int o = t, c = 0; c < 3; ++c, o += 256)
    wh_ent[o] = whp[0][o] + whp[1][o] + whp[2][o] + whp[3][o];
  // rowwise softmax max = leaky(e1 + max_j e2)
  {
    float p = fmaxf(e2s[w * 128 + l], e2s[w * 128 + 64 + l]);
    #pragma unroll
    for (int d = 1; d < 64; d <<= 1) p = fmaxf(p, __shfl_xor(p, d));
    if (l == 0) redw[w] = p;
  }
  __syncthreads();

  float maxe2 = fmaxf(fmaxf(redw[0], redw[1]), fmaxf(redw[2], redw[3]));
  for (int r = 0; r < R; ++r) {
    float e1_ = e1r[r];
    float m_ = leaky_(e1_ + maxe2);
    float pe = __expf(leaky_(e1_ + e2s[t]) - m_) + __expf(leaky_(e1_ + e2s[t + 256]) - m_);
    #pragma unroll
    for (int d = 1; d < 64; d <<= 1) pe += __shfl_xor(pe, d);
    if (l == 0) red4[r * 4 + w] = pe;
    if (t == r) mr[r] = m_;
  }
  __syncthreads();
  if (t < R) sr[t] = red4[t * 4] + red4[t * 4 + 1] + red4[t * 4 + 2] + red4[t * 4 + 3];
  __syncthreads();
  if (t < M) {
    int r = shdr[I_ER + t];
    avals[t] = __expf(leaky_(e1r[r] + e2s[shdr[I_EJ + t]]) - mr[r]) / sr[r];
  }
  __syncthreads();

  for (int r = w; r < R; r += 4) {
    float a = 0.f;
    #pragma unroll
    for (int m = 0; m < 12; ++m) {
      if (m < M && shdr[I_ER + m] == r) a += avals[m] * wh_ent[m * 64 + l];
    }
    wsf[MIDC_OFF + r * 32768 + h * 64 + l] = elu_(a);
  }
}

// K7: Wh2 partials: block b covers mid columns [b*256, b*256+256). W_out read exactly once.
__global__ void k7_wh2(const float* __restrict__ Wout, float* __restrict__ wsf) {
  __shared__ __align__(16) float midT[256 * 12];
  __shared__ float whp[4][768];
  int b = blockIdx.x, t = threadIdx.x;
  int l = t & 63, w = t >> 6;
  const int* ip = (const int*)(wsf + INT_OFF);
  int R = ip[I_R];
  #pragma unroll
  for (int m = 0; m < 12; ++m) {
    float v = 0.f;
    if (m < R) v = wsf[MIDC_OFF + m * 32768 + b * 256 + t];
    midT[t * 12 + m] = v;
  }
  __syncthreads();
  float acc[12];
  #pragma unroll
  for (int m = 0; m < 12; ++m) acc[m] = 0.f;
  #pragma unroll 2
  for (int ci = 0; ci < 64; ++ci) {
    int cc = w * 64 + ci;
    float wv = Wout[(b * 256 + cc) * 64 + l];
    const float4* xr = reinterpret_cast<const float4*>(&midT[cc * 12]);
    float4 xa = xr[0], xb = xr[1], xc = xr[2];
    acc[0] += xa.x * wv; acc[1] += xa.y * wv; acc[2]  += xa.z * wv; acc[3]  += xa.w * wv;
    acc[4] += xb.x * wv; acc[5] += xb.y * wv; acc[6]  += xb.z * wv; acc[7]  += xb.w * wv;
    acc[8] += xc.x * wv; acc[9] += xc.y * wv; acc[10] += xc.z * wv; acc[11] += xc.w * wv;
  }
  #pragma unroll
  for (int m = 0; m < 12; ++m) whp[w][m * 64 + l] = acc[m];
  __syncthreads();
  for (int o = t, c = 0; c < 3; ++c, o += 256) {
    float s = whp[0][o] + whp[1][o] + whp[2][o] + whp[3][o];
    wsf[PART_OFF + o * 128 + b] = s;
  }
}

// K8: reduce Wh2 partials; layer-2 GAT with closed-form softmax over implicit zeros; final elu(V*elu(out2))
__global__ void k8_final(const float* __restrict__ aout, const float* __restrict__ V,
                         float* __restrict__ wsf, float* __restrict__ out) {
  __shared__ float Wh2[768];
  __shared__ float e1o[12], e2o[12], mr[12], sr[12], avals[12];
  int t = threadIdx.x;
  const int* ip = (const int*)(wsf + INT_OFF);
  int M = ip[I_M], R = ip[I_R];
  for (int o = t, c = 0; c < 3; ++c, o += 256) {
    float s = 0.f;
    const float4* p4 = reinterpret_cast<const float4*>(wsf + PART_OFF + o * 128);
    #pragma unroll 4
    for (int q = 0; q < 32; ++q) { float4 v = p4[q]; s += v.x + v.y + v.z + v.w; }
    Wh2[o] = s;
  }
  __syncthreads();
  if (t < R) {
    float s1 = 0.f, s2 = 0.f;
    for (int k = 0; k < 64; ++k) {
      float wv = Wh2[t * 64 + k];
      s1 += wv * aout[k];
      s2 += wv * aout[64 + k];
    }
    e1o[t] = s1; e2o[t] = s2;
  }
  __syncthreads();
  if (t < R) {
    float maxe = 0.f;  // includes the (512-R) implicit zeros
    for (int r = 0; r < R; ++r) maxe = fmaxf(maxe, e2o[r]);
    float m_ = leaky_(e1o[t] + maxe);
    float s = (float)(512 - R) * __expf(leaky_(e1o[t]) - m_);
    for (int r = 0; r < R; ++r) s += __expf(leaky_(e1o[t] + e2o[r]) - m_);
    mr[t] = m_; sr[t] = s;
  }
  __syncthreads();
  if (t < M) {
    int r = ip[I_ER + t];
    int cj = ip[I_ECJ + t];
    float e2v = (cj >= 0) ? e2o[cj] : 0.f;
    avals[t] = __expf(leaky_(e1o[r] + e2v) - mr[r]) / sr[r];
  }
  __syncthreads();
  int l = t & 63, w = t >> 6;
  for (int r = w; r < R; r += 4) {
    float a = 0.f;
    #pragma unroll
    for (int m = 0; m < 12; ++m) {
      if (m < M && ip[I_ER + m] == r) {
        int cj = ip[I_ECJ + m];
        float wv = (cj >= 0) ? Wh2[cj * 64 + l] : 0.f;
        a += avals[m] * wv;
      }
    }
    int row = ip[I_ROWS + r];
    float o2 = elu_(a);
    out[262144 + row * 64 + l] = elu_(V[row * 64 + l] * o2);
  }
}

extern "C" void kernel_launch(void* const* d_in, const int* in_sizes, int n_in,
                              void* d_out, int out_size, void* d_ws, size_t ws_size,
                              hipStream_t stream) {
  const float* X    = (const float*)d_in[0];
  const float* Wst  = (const float*)d_in[1];
  const float* ast  = (const float*)d_in[2];
  const float* Wout = (const float*)d_in[3];
  const float* aout = (const float*)d_in[4];
  const float* V    = (const float*)d_in[5];
  float* out = (float*)d_out;
  float* wsf = (float*)d_ws;

  k1_prep      <<<704, 256, 0, stream>>>(V, X, wsf, out);
  k2_topk_block<<<256, 256, 0, stream>>>(out, wsf);
  k3_topk_final<<<1,   256, 0, stream>>>(wsf);
  k4_adj       <<<256, 256, 0, stream>>>(out, wsf);
  k5_finalize  <<<1,    64, 0, stream>>>(wsf);
  k6_heads     <<<512, 256, 0, stream>>>(X, Wst, ast, wsf);
  k7_wh2       <<<128, 256, 0, stream>>>(Wout, wsf);
  k8_final     <<<1,   256, 0, stream>>>(aout, V, wsf, out);
}